// Round 1
// baseline (2338.997 us; speedup 1.0000x reference)
//
#include <hip/hip_runtime.h>
#include <cmath>

#define MROWS  4096   // B*L
#define DMODEL 1024
#define DINNER 2048
#define DSTATE 16
#define DTRANK 64
#define NDBL   96     // DTRANK + 2*DSTATE
#define LSEQ   2048

// ---------------- LayerNorm: one block per row ----------------
__global__ __launch_bounds__(256) void ln_kernel(const float* __restrict__ seq,
                                                 const float* __restrict__ g,
                                                 const float* __restrict__ bta,
                                                 float* __restrict__ xn) {
    int row = blockIdx.x;
    int t = threadIdx.x;                    // 256 threads * 4 floats = 1024
    const float4* in4 = (const float4*)(seq + (size_t)row * DMODEL);
    float4 v = in4[t];
    float s  = v.x + v.y + v.z + v.w;
    float s2 = v.x*v.x + v.y*v.y + v.z*v.z + v.w*v.w;
    for (int off = 32; off; off >>= 1) {
        s  += __shfl_down(s,  off, 64);
        s2 += __shfl_down(s2, off, 64);
    }
    __shared__ float ss[4], ss2[4];
    int wid = t >> 6;
    if ((t & 63) == 0) { ss[wid] = s; ss2[wid] = s2; }
    __syncthreads();
    s  = ss[0] + ss[1] + ss[2] + ss[3];
    s2 = ss2[0] + ss2[1] + ss2[2] + ss2[3];
    float mu  = s * (1.0f / DMODEL);
    float var = s2 * (1.0f / DMODEL) - mu * mu;
    float rs  = rsqrtf(var + 1e-5f);
    float4 gg = ((const float4*)g)[t];
    float4 bb = ((const float4*)bta)[t];
    float4 o;
    o.x = (v.x - mu) * rs * gg.x + bb.x;
    o.y = (v.y - mu) * rs * gg.y + bb.y;
    o.z = (v.z - mu) * rs * gg.z + bb.z;
    o.w = (v.w - mu) * rs * gg.w + bb.w;
    ((float4*)(xn + (size_t)row * DMODEL))[t] = o;
}

__device__ __forceinline__ float softplusf(float x) {
    return x > 20.f ? x : log1pf(expf(x));
}

// ---------------- Generic NT fp32 GEMM: C[m,n] = dot(A[m,:], B[n,:]) ----------
// 64x64 tile, K-tile 16, 256 threads, 4x4 microtile.
// EPI 0: plain store. EPI 1: softplus(acc + e0[n]). EPI 2: e0[m*ldc+n] + (*e1)*acc.
template <int EPI>
__global__ __launch_bounds__(256) void gemm_nt(const float* __restrict__ A, int lda,
                                               const float* __restrict__ B, int ldb,
                                               float* __restrict__ C, int ldc,
                                               int M, int N, int K,
                                               const float* __restrict__ e0,
                                               const float* __restrict__ e1) {
    __shared__ float As[16][68];   // [k][m], pad 68 keeps float4 alignment (272B rows)
    __shared__ float Bs[16][68];   // [k][n]
    const int m0 = blockIdx.x * 64, n0 = blockIdx.y * 64;
    const int tid = threadIdx.x;
    const int lr = tid >> 2;            // 0..63 tile row
    const int lk = (tid & 3) << 2;      // 0,4,8,12
    const int tx = tid & 15;            // m-frag
    const int ty = tid >> 4;            // n-frag
    float acc[4][4] = {};

    for (int k0 = 0; k0 < K; k0 += 16) {
        float4 av = *(const float4*)(A + (size_t)(m0 + lr) * lda + k0 + lk);
        float4 bv = make_float4(0.f, 0.f, 0.f, 0.f);
        int brow = n0 + lr;
        if (brow < N) bv = *(const float4*)(B + (size_t)brow * ldb + k0 + lk);
        __syncthreads();
        As[lk + 0][lr] = av.x; As[lk + 1][lr] = av.y;
        As[lk + 2][lr] = av.z; As[lk + 3][lr] = av.w;
        Bs[lk + 0][lr] = bv.x; Bs[lk + 1][lr] = bv.y;
        Bs[lk + 2][lr] = bv.z; Bs[lk + 3][lr] = bv.w;
        __syncthreads();
#pragma unroll
        for (int kk = 0; kk < 16; kk++) {
            float4 a = *(const float4*)&As[kk][tx * 4];
            float4 b = *(const float4*)&Bs[kk][ty * 4];
            acc[0][0] += a.x * b.x; acc[0][1] += a.x * b.y; acc[0][2] += a.x * b.z; acc[0][3] += a.x * b.w;
            acc[1][0] += a.y * b.x; acc[1][1] += a.y * b.y; acc[1][2] += a.y * b.z; acc[1][3] += a.y * b.w;
            acc[2][0] += a.z * b.x; acc[2][1] += a.z * b.y; acc[2][2] += a.z * b.z; acc[2][3] += a.z * b.w;
            acc[3][0] += a.w * b.x; acc[3][1] += a.w * b.y; acc[3][2] += a.w * b.z; acc[3][3] += a.w * b.w;
        }
    }

    const int n = n0 + ty * 4;
    if (n < N) {
#pragma unroll
        for (int i = 0; i < 4; i++) {
            int m = m0 + tx * 4 + i;
            float4 o;
            if (EPI == 0) {
                o = make_float4(acc[i][0], acc[i][1], acc[i][2], acc[i][3]);
            } else if (EPI == 1) {
                o.x = softplusf(acc[i][0] + e0[n + 0]);
                o.y = softplusf(acc[i][1] + e0[n + 1]);
                o.z = softplusf(acc[i][2] + e0[n + 2]);
                o.w = softplusf(acc[i][3] + e0[n + 3]);
            } else {
                float rs = *e1;
                const float4 sv = *(const float4*)(e0 + (size_t)m * ldc + n);
                o.x = sv.x + rs * acc[i][0];
                o.y = sv.y + rs * acc[i][1];
                o.z = sv.z + rs * acc[i][2];
                o.w = sv.w + rs * acc[i][3];
            }
            *(float4*)(C + (size_t)m * ldc + n) = o;
        }
    }
}

// ---------------- depthwise causal conv (k=4) + SiLU ----------------
__global__ __launch_bounds__(256) void conv_silu(const float* __restrict__ xz,
                                                 const float* __restrict__ cw,
                                                 const float* __restrict__ cb,
                                                 float* __restrict__ xc) {
    int idx = blockIdx.x * 256 + threadIdx.x;    // over MROWS*DINNER
    int d = idx & (DINNER - 1);
    int m = idx >> 11;
    int t = m & (LSEQ - 1);
    float v = cb[d];
#pragma unroll
    for (int k = 0; k < 4; k++) {
        int tt = t - 3 + k;
        if (tt >= 0) v += xz[(size_t)(m - 3 + k) * (2 * DINNER) + d] * cw[d * 4 + k];
    }
    v = v / (1.f + expf(-v));
    xc[idx] = v;
}

// ---------------- selective scan: 16 lanes per channel ----------------
// dty: dt in, y out (in-place, same slot, read-before-write within the wave)
__global__ __launch_bounds__(256) void scan_kernel(float* dty,
                                                   const float* __restrict__ xc,
                                                   const float* __restrict__ xdbl,
                                                   const float* __restrict__ xz,
                                                   const float* __restrict__ A_log,
                                                   const float* __restrict__ Dp) {
    const int g = threadIdx.x >> 4;
    const int s = threadIdx.x & 15;
    const int c = blockIdx.x * 16 + g;       // 0..4095 = (b,d)
    const int b = c >> 11;
    const int d = c & (DINNER - 1);
    const float A  = -expf(A_log[d * DSTATE + s]);
    const float Dd = Dp[d];
    const size_t base = (size_t)b * LSEQ;
    float h = 0.f;
    // prefetch t=0
    float dtv = dty[base * DINNER + d];
    float xv  = xc[base * DINNER + d];
    float Bv  = xdbl[base * NDBL + DTRANK + s];
    float Cv  = xdbl[base * NDBL + DTRANK + DSTATE + s];
    for (int t = 0; t < LSEQ; t++) {
        float dtn = 0.f, xn2 = 0.f, Bn = 0.f, Cn = 0.f;
        if (t + 1 < LSEQ) {
            size_t m2 = base + t + 1;
            dtn = dty[m2 * DINNER + d];
            xn2 = xc[m2 * DINNER + d];
            Bn  = xdbl[m2 * NDBL + DTRANK + s];
            Cn  = xdbl[m2 * NDBL + DTRANK + DSTATE + s];
        }
        float dA = expf(dtv * A);
        h = h * dA + (dtv * xv) * Bv;
        float p = h * Cv;
        p += __shfl_xor(p, 1, 16);
        p += __shfl_xor(p, 2, 16);
        p += __shfl_xor(p, 4, 16);
        p += __shfl_xor(p, 8, 16);
        if (s == 0) {
            size_t mi = base + t;
            float yv = p + Dd * xv;
            float zv = xz[mi * (2 * DINNER) + DINNER + d];
            yv *= zv / (1.f + expf(-zv));
            dty[mi * DINNER + d] = yv;       // y overwrites dt slot
        }
        dtv = dtn; xv = xn2; Bv = Bn; Cv = Cn;
    }
}

extern "C" void kernel_launch(void* const* d_in, const int* in_sizes, int n_in,
                              void* d_out, int out_size, void* d_ws, size_t ws_size,
                              hipStream_t stream) {
    const float* seq       = (const float*)d_in[0];
    const float* ln_g      = (const float*)d_in[1];
    const float* ln_b      = (const float*)d_in[2];
    const float* in_proj_w = (const float*)d_in[3];
    const float* conv_w    = (const float*)d_in[4];
    const float* conv_b    = (const float*)d_in[5];
    const float* x_proj_w  = (const float*)d_in[6];
    const float* dt_proj_w = (const float*)d_in[7];
    const float* dt_proj_b = (const float*)d_in[8];
    const float* A_log     = (const float*)d_in[9];
    const float* Dp        = (const float*)d_in[10];
    const float* out_proj_w= (const float*)d_in[11];
    const float* res_scale = (const float*)d_in[12];

    float* ws   = (float*)d_ws;
    float* xz   = ws;                       // 4096*4096 = 16,777,216 floats
    float* xc   = xz + 16777216;            // 4096*2048 =  8,388,608
    float* dty  = xc + 8388608;             // 4096*2048 =  8,388,608 (dt, then y)
    float* xn   = dty + 8388608;            // 4096*1024 =  4,194,304 (xn, then x_dbl)
    float* xdbl = xn;                       // 4096*96 aliases dead xn

    ln_kernel<<<MROWS, 256, 0, stream>>>(seq, ln_g, ln_b, xn);

    // xz = xn @ in_proj_w^T   (M=4096, N=4096, K=1024)
    gemm_nt<0><<<dim3(64, 64), 256, 0, stream>>>(xn, DMODEL, in_proj_w, DMODEL,
                                                 xz, 2 * DINNER, MROWS, 2 * DINNER, DMODEL,
                                                 nullptr, nullptr);

    conv_silu<<<(MROWS * DINNER) / 256, 256, 0, stream>>>(xz, conv_w, conv_b, xc);

    // x_dbl = xc @ x_proj_w^T   (M=4096, N=96, K=2048)
    gemm_nt<0><<<dim3(64, 2), 256, 0, stream>>>(xc, DINNER, x_proj_w, DINNER,
                                                xdbl, NDBL, MROWS, NDBL, DINNER,
                                                nullptr, nullptr);

    // dt = softplus(x_dbl[:, :64] @ dt_proj_w^T + b)   (M=4096, N=2048, K=64)
    gemm_nt<1><<<dim3(64, 32), 256, 0, stream>>>(xdbl, NDBL, dt_proj_w, DTRANK,
                                                 dty, DINNER, MROWS, DINNER, DTRANK,
                                                 dt_proj_b, nullptr);

    scan_kernel<<<MROWS / 16, 256, 0, stream>>>(dty, xc, xdbl, xz, A_log, Dp);

    // out = seq + rs * (y @ out_proj_w^T)   (M=4096, N=1024, K=2048)
    gemm_nt<2><<<dim3(64, 16), 256, 0, stream>>>(dty, DINNER, out_proj_w, DINNER,
                                                 (float*)d_out, DMODEL, MROWS, DMODEL, DINNER,
                                                 seq, res_scale);
}

// Round 2
// 1171.926 us; speedup vs baseline: 1.9959x; 1.9959x over previous
//
#include <hip/hip_runtime.h>
#include <cmath>

#define MROWS  4096   // B*L
#define DMODEL 1024
#define DINNER 2048
#define DSTATE 16
#define DTRANK 64
#define NDBL   96     // DTRANK + 2*DSTATE
#define LSEQ   2048
#define LCHUNK 32
#define NCHUNK 64     // LSEQ / LCHUNK

// ---------------- LayerNorm: one block per row ----------------
__global__ __launch_bounds__(256) void ln_kernel(const float* __restrict__ seq,
                                                 const float* __restrict__ g,
                                                 const float* __restrict__ bta,
                                                 float* __restrict__ xn) {
    int row = blockIdx.x;
    int t = threadIdx.x;                    // 256 threads * 4 floats = 1024
    const float4* in4 = (const float4*)(seq + (size_t)row * DMODEL);
    float4 v = in4[t];
    float s  = v.x + v.y + v.z + v.w;
    float s2 = v.x*v.x + v.y*v.y + v.z*v.z + v.w*v.w;
    for (int off = 32; off; off >>= 1) {
        s  += __shfl_down(s,  off, 64);
        s2 += __shfl_down(s2, off, 64);
    }
    __shared__ float ss[4], ss2[4];
    int wid = t >> 6;
    if ((t & 63) == 0) { ss[wid] = s; ss2[wid] = s2; }
    __syncthreads();
    s  = ss[0] + ss[1] + ss[2] + ss[3];
    s2 = ss2[0] + ss2[1] + ss2[2] + ss2[3];
    float mu  = s * (1.0f / DMODEL);
    float var = s2 * (1.0f / DMODEL) - mu * mu;
    float rs  = rsqrtf(var + 1e-5f);
    float4 gg = ((const float4*)g)[t];
    float4 bb = ((const float4*)bta)[t];
    float4 o;
    o.x = (v.x - mu) * rs * gg.x + bb.x;
    o.y = (v.y - mu) * rs * gg.y + bb.y;
    o.z = (v.z - mu) * rs * gg.z + bb.z;
    o.w = (v.w - mu) * rs * gg.w + bb.w;
    ((float4*)(xn + (size_t)row * DMODEL))[t] = o;
}

__device__ __forceinline__ float softplusf(float x) {
    return x > 20.f ? x : log1pf(expf(x));
}

// ---------------- Generic NT fp32 GEMM: C[m,n] = dot(A[m,:], B[n,:]) ----------
template <int EPI>
__global__ __launch_bounds__(256) void gemm_nt(const float* __restrict__ A, int lda,
                                               const float* __restrict__ B, int ldb,
                                               float* __restrict__ C, int ldc,
                                               int M, int N, int K,
                                               const float* __restrict__ e0,
                                               const float* __restrict__ e1) {
    __shared__ float As[16][68];
    __shared__ float Bs[16][68];
    const int m0 = blockIdx.x * 64, n0 = blockIdx.y * 64;
    const int tid = threadIdx.x;
    const int lr = tid >> 2;
    const int lk = (tid & 3) << 2;
    const int tx = tid & 15;
    const int ty = tid >> 4;
    float acc[4][4] = {};

    for (int k0 = 0; k0 < K; k0 += 16) {
        float4 av = *(const float4*)(A + (size_t)(m0 + lr) * lda + k0 + lk);
        float4 bv = make_float4(0.f, 0.f, 0.f, 0.f);
        int brow = n0 + lr;
        if (brow < N) bv = *(const float4*)(B + (size_t)brow * ldb + k0 + lk);
        __syncthreads();
        As[lk + 0][lr] = av.x; As[lk + 1][lr] = av.y;
        As[lk + 2][lr] = av.z; As[lk + 3][lr] = av.w;
        Bs[lk + 0][lr] = bv.x; Bs[lk + 1][lr] = bv.y;
        Bs[lk + 2][lr] = bv.z; Bs[lk + 3][lr] = bv.w;
        __syncthreads();
#pragma unroll
        for (int kk = 0; kk < 16; kk++) {
            float4 a = *(const float4*)&As[kk][tx * 4];
            float4 b = *(const float4*)&Bs[kk][ty * 4];
            acc[0][0] += a.x * b.x; acc[0][1] += a.x * b.y; acc[0][2] += a.x * b.z; acc[0][3] += a.x * b.w;
            acc[1][0] += a.y * b.x; acc[1][1] += a.y * b.y; acc[1][2] += a.y * b.z; acc[1][3] += a.y * b.w;
            acc[2][0] += a.z * b.x; acc[2][1] += a.z * b.y; acc[2][2] += a.z * b.z; acc[2][3] += a.z * b.w;
            acc[3][0] += a.w * b.x; acc[3][1] += a.w * b.y; acc[3][2] += a.w * b.z; acc[3][3] += a.w * b.w;
        }
    }

    const int n = n0 + ty * 4;
    if (n < N) {
#pragma unroll
        for (int i = 0; i < 4; i++) {
            int m = m0 + tx * 4 + i;
            float4 o;
            if (EPI == 0) {
                o = make_float4(acc[i][0], acc[i][1], acc[i][2], acc[i][3]);
            } else if (EPI == 1) {
                o.x = softplusf(acc[i][0] + e0[n + 0]);
                o.y = softplusf(acc[i][1] + e0[n + 1]);
                o.z = softplusf(acc[i][2] + e0[n + 2]);
                o.w = softplusf(acc[i][3] + e0[n + 3]);
            } else {
                float rs = *e1;
                const float4 sv = *(const float4*)(e0 + (size_t)m * ldc + n);
                o.x = sv.x + rs * acc[i][0];
                o.y = sv.y + rs * acc[i][1];
                o.z = sv.z + rs * acc[i][2];
                o.w = sv.w + rs * acc[i][3];
            }
            *(float4*)(C + (size_t)m * ldc + n) = o;
        }
    }
}

// ---------------- depthwise causal conv (k=4) + SiLU ----------------
__global__ __launch_bounds__(256) void conv_silu(const float* __restrict__ xz,
                                                 const float* __restrict__ cw,
                                                 const float* __restrict__ cb,
                                                 float* __restrict__ xc) {
    int idx = blockIdx.x * 256 + threadIdx.x;    // over MROWS*DINNER
    int d = idx & (DINNER - 1);
    int m = idx >> 11;
    int t = m & (LSEQ - 1);
    float v = cb[d];
#pragma unroll
    for (int k = 0; k < 4; k++) {
        int tt = t - 3 + k;
        if (tt >= 0) v += xz[(size_t)(m - 3 + k) * (2 * DINNER) + d] * cw[d * 4 + k];
    }
    v = v / (1.f + __expf(-v));
    xc[idx] = v;
}

// ---------------- selective scan, chunked 3-pass ----------------
// Pass 1: per (b, chunk, d): P[s] = prod dA, S[s] = local state from h=0.
__global__ __launch_bounds__(256) void scan_pass1(const float* __restrict__ dt,
                                                  const float* __restrict__ xc,
                                                  const float* __restrict__ xdbl,
                                                  const float* __restrict__ A_log,
                                                  float* __restrict__ Pp,
                                                  float* __restrict__ Sp) {
    const int d = blockIdx.x * 256 + threadIdx.x;
    const int c = blockIdx.y;
    const int b = blockIdx.z;
    __shared__ float Bsm[LCHUNK][DSTATE];
    const size_t rowbase = (size_t)b * LSEQ + (size_t)c * LCHUNK;
    for (int idx = threadIdx.x; idx < LCHUNK * DSTATE; idx += 256) {
        int i = idx >> 4, j = idx & 15;
        Bsm[i][j] = xdbl[(rowbase + i) * NDBL + DTRANK + j];
    }
    __syncthreads();
    float A[DSTATE], P[DSTATE], S[DSTATE];
#pragma unroll
    for (int s = 0; s < DSTATE; s++) {
        A[s] = -__expf(A_log[d * DSTATE + s]);
        P[s] = 1.f; S[s] = 0.f;
    }
    for (int t = 0; t < LCHUNK; t++) {
        float dtv = dt[(rowbase + t) * DINNER + d];
        float xv  = xc[(rowbase + t) * DINNER + d];
        float du = dtv * xv;
#pragma unroll
        for (int s = 0; s < DSTATE; s++) {
            float dA = __expf(dtv * A[s]);
            P[s] *= dA;
            S[s] = S[s] * dA + du * Bsm[t][s];
        }
    }
    const size_t obase = (((size_t)c * 2 + b) * DINNER + d) * DSTATE;
#pragma unroll
    for (int s = 0; s < DSTATE; s++) { Pp[obase + s] = P[s]; Sp[obase + s] = S[s]; }
}

// Pass 2: 65536 threads, serial over chunks; writes h_init[c] over Pp[c].
__global__ __launch_bounds__(256) void scan_pass2(float* __restrict__ Pp,
                                                  const float* __restrict__ Sp) {
    const int gid = blockIdx.x * 256 + threadIdx.x;   // (b*DINNER+d)*16+s
    const int b = gid >> 15;
    const int rest = gid & 32767;                     // d*16+s
    float h = 0.f;
    for (int c = 0; c < NCHUNK; c++) {
        size_t idx = ((size_t)(c * 2 + b) << 15) + rest;
        float p = Pp[idx];
        float s = Sp[idx];
        Pp[idx] = h;                                  // h_init for chunk c
        h = p * h + s;
    }
}

// Pass 3: recompute from h_init; fuse y = (sum h*C) + D*x, z-gate; y over dt.
__global__ __launch_bounds__(256) void scan_pass3(float* __restrict__ dty,
                                                  const float* __restrict__ xc,
                                                  const float* __restrict__ xdbl,
                                                  const float* __restrict__ xz,
                                                  const float* __restrict__ A_log,
                                                  const float* __restrict__ Dp,
                                                  const float* __restrict__ Hinit) {
    const int d = blockIdx.x * 256 + threadIdx.x;
    const int c = blockIdx.y;
    const int b = blockIdx.z;
    __shared__ float Bsm[LCHUNK][DSTATE];
    __shared__ float Csm[LCHUNK][DSTATE];
    const size_t rowbase = (size_t)b * LSEQ + (size_t)c * LCHUNK;
    for (int idx = threadIdx.x; idx < LCHUNK * DSTATE; idx += 256) {
        int i = idx >> 4, j = idx & 15;
        Bsm[i][j] = xdbl[(rowbase + i) * NDBL + DTRANK + j];
        Csm[i][j] = xdbl[(rowbase + i) * NDBL + DTRANK + DSTATE + j];
    }
    __syncthreads();
    float A[DSTATE], h[DSTATE];
    const size_t hbase = (((size_t)c * 2 + b) * DINNER + d) * DSTATE;
#pragma unroll
    for (int s = 0; s < DSTATE; s++) {
        A[s] = -__expf(A_log[d * DSTATE + s]);
        h[s] = Hinit[hbase + s];
    }
    const float Dd = Dp[d];
    for (int t = 0; t < LCHUNK; t++) {
        const size_t mi = rowbase + t;
        float dtv = dty[mi * DINNER + d];
        float xv  = xc[mi * DINNER + d];
        float du = dtv * xv;
        float y = 0.f;
#pragma unroll
        for (int s = 0; s < DSTATE; s++) {
            float dA = __expf(dtv * A[s]);
            h[s] = h[s] * dA + du * Bsm[t][s];
            y += h[s] * Csm[t][s];
        }
        y += Dd * xv;
        float zv = xz[mi * (2 * DINNER) + DINNER + d];
        y *= zv / (1.f + __expf(-zv));
        dty[mi * DINNER + d] = y;
    }
}

extern "C" void kernel_launch(void* const* d_in, const int* in_sizes, int n_in,
                              void* d_out, int out_size, void* d_ws, size_t ws_size,
                              hipStream_t stream) {
    const float* seq       = (const float*)d_in[0];
    const float* ln_g      = (const float*)d_in[1];
    const float* ln_b      = (const float*)d_in[2];
    const float* in_proj_w = (const float*)d_in[3];
    const float* conv_w    = (const float*)d_in[4];
    const float* conv_b    = (const float*)d_in[5];
    const float* x_proj_w  = (const float*)d_in[6];
    const float* dt_proj_w = (const float*)d_in[7];
    const float* dt_proj_b = (const float*)d_in[8];
    const float* A_log     = (const float*)d_in[9];
    const float* Dp        = (const float*)d_in[10];
    const float* out_proj_w= (const float*)d_in[11];
    const float* res_scale = (const float*)d_in[12];

    float* ws   = (float*)d_ws;
    float* xz   = ws;                       // 16,777,216 floats
    float* xc   = xz + 16777216;            //  8,388,608
    float* dty  = xc + 8388608;             //  8,388,608 (dt, then y)
    float* xn   = dty + 8388608;            //  4,194,304 (xn, then x_dbl)
    float* xdbl = xn;                       // aliases dead xn
    float* Pp   = xn + 4194304;             //  4,194,304 (P, then h_init)
    float* Sp   = Pp + 4194304;             //  4,194,304

    ln_kernel<<<MROWS, 256, 0, stream>>>(seq, ln_g, ln_b, xn);

    // xz = xn @ in_proj_w^T   (M=4096, N=4096, K=1024)
    gemm_nt<0><<<dim3(64, 64), 256, 0, stream>>>(xn, DMODEL, in_proj_w, DMODEL,
                                                 xz, 2 * DINNER, MROWS, 2 * DINNER, DMODEL,
                                                 nullptr, nullptr);

    conv_silu<<<(MROWS * DINNER) / 256, 256, 0, stream>>>(xz, conv_w, conv_b, xc);

    // x_dbl = xc @ x_proj_w^T   (M=4096, N=96, K=2048)
    gemm_nt<0><<<dim3(64, 2), 256, 0, stream>>>(xc, DINNER, x_proj_w, DINNER,
                                                xdbl, NDBL, MROWS, NDBL, DINNER,
                                                nullptr, nullptr);

    // dt = softplus(x_dbl[:, :64] @ dt_proj_w^T + b)   (M=4096, N=2048, K=64)
    gemm_nt<1><<<dim3(64, 32), 256, 0, stream>>>(xdbl, NDBL, dt_proj_w, DTRANK,
                                                 dty, DINNER, MROWS, DINNER, DTRANK,
                                                 dt_proj_b, nullptr);

    // chunked selective scan
    scan_pass1<<<dim3(DINNER / 256, NCHUNK, 2), 256, 0, stream>>>(dty, xc, xdbl, A_log, Pp, Sp);
    scan_pass2<<<(2 * DINNER * DSTATE) / 256, 256, 0, stream>>>(Pp, Sp);
    scan_pass3<<<dim3(DINNER / 256, NCHUNK, 2), 256, 0, stream>>>(dty, xc, xdbl, xz, A_log, Dp, Pp);

    // out = seq + rs * (y @ out_proj_w^T)   (M=4096, N=1024, K=2048)
    gemm_nt<2><<<dim3(64, 16), 256, 0, stream>>>(dty, DINNER, out_proj_w, DINNER,
                                                 (float*)d_out, DMODEL, MROWS, DMODEL, DINNER,
                                                 seq, res_scale);
}

// Round 3
// 498.611 us; speedup vs baseline: 4.6910x; 2.3504x over previous
//
#include <hip/hip_runtime.h>
#include <cmath>

#define MROWS  4096   // B*L
#define DMODEL 1024
#define DINNER 2048
#define DSTATE 16
#define DTRANK 64
#define NDBL   96     // DTRANK + 2*DSTATE
#define LSEQ   2048
#define LCHUNK 32
#define NCHUNK 64     // LSEQ / LCHUNK

typedef __attribute__((ext_vector_type(8))) short short8;
typedef __attribute__((ext_vector_type(4))) float floatx4;

__device__ __forceinline__ unsigned short f2bf(float x) {   // RNE fp32->bf16
    union { float f; unsigned u; } v; v.f = x;
    unsigned r = v.u + 0x7fff + ((v.u >> 16) & 1);
    return (unsigned short)(r >> 16);
}

#define GLOAD_LDS16(g, l) \
    __builtin_amdgcn_global_load_lds((const __attribute__((address_space(1))) unsigned int*)(g), \
                                     (__attribute__((address_space(3))) unsigned int*)(l), 16, 0, 0)

// ---------------- weight fp32 -> bf16 convert (both proj weights) ----------------
__global__ __launch_bounds__(256) void convert_w(const float* __restrict__ w_in,
                                                 const float* __restrict__ w_out,
                                                 unsigned short* __restrict__ win_bf,
                                                 unsigned short* __restrict__ wout_bf) {
    int idx = blockIdx.x * 256 + threadIdx.x;          // float4 index
    const float4* src; unsigned short* dst; int i;
    if (idx < 1048576) { src = (const float4*)w_in;  dst = win_bf;  i = idx; }
    else               { src = (const float4*)w_out; dst = wout_bf; i = idx - 1048576; }
    float4 v = src[i];
    ushort4 o;
    o.x = f2bf(v.x); o.y = f2bf(v.y); o.z = f2bf(v.z); o.w = f2bf(v.w);
    *(ushort4*)(dst + (size_t)i * 4) = o;
}

// ---------------- LayerNorm: one block per row, bf16 output ----------------
__global__ __launch_bounds__(256) void ln_kernel(const float* __restrict__ seq,
                                                 const float* __restrict__ g,
                                                 const float* __restrict__ bta,
                                                 unsigned short* __restrict__ xn_bf) {
    int row = blockIdx.x;
    int t = threadIdx.x;
    const float4* in4 = (const float4*)(seq + (size_t)row * DMODEL);
    float4 v = in4[t];
    float s  = v.x + v.y + v.z + v.w;
    float s2 = v.x*v.x + v.y*v.y + v.z*v.z + v.w*v.w;
    for (int off = 32; off; off >>= 1) {
        s  += __shfl_down(s,  off, 64);
        s2 += __shfl_down(s2, off, 64);
    }
    __shared__ float ss[4], ss2[4];
    int wid = t >> 6;
    if ((t & 63) == 0) { ss[wid] = s; ss2[wid] = s2; }
    __syncthreads();
    s  = ss[0] + ss[1] + ss[2] + ss[3];
    s2 = ss2[0] + ss2[1] + ss2[2] + ss2[3];
    float mu  = s * (1.0f / DMODEL);
    float var = s2 * (1.0f / DMODEL) - mu * mu;
    float rs  = rsqrtf(var + 1e-5f);
    float4 gg = ((const float4*)g)[t];
    float4 bb = ((const float4*)bta)[t];
    ushort4 o;
    o.x = f2bf((v.x - mu) * rs * gg.x + bb.x);
    o.y = f2bf((v.y - mu) * rs * gg.y + bb.y);
    o.z = f2bf((v.z - mu) * rs * gg.z + bb.z);
    o.w = f2bf((v.w - mu) * rs * gg.w + bb.w);
    *(ushort4*)(xn_bf + (size_t)row * DMODEL + t * 4) = o;
}

// ---------------- bf16 MFMA NT GEMM: C[m,n] = dot(A[m,:], B[n,:]) ----------------
// 128x128 tile, BK=32, 4 waves (2x2), each wave 64x64 via 4x4 of 16x16x32 MFMA.
// EPI 0: plain fp32 store. EPI 2: C = e0[m*ldc+n] + (*e1)*acc  (residual).
template <int EPI>
__global__ __launch_bounds__(256) void gemm_bf16(const unsigned short* __restrict__ A, int lda,
                                                 const unsigned short* __restrict__ B, int ldb,
                                                 float* __restrict__ C, int ldc, int K,
                                                 const float* __restrict__ e0,
                                                 const float* __restrict__ e1) {
    __shared__ short As[128 * 32];
    __shared__ short Bs[128 * 32];
    const int tid  = threadIdx.x;
    const int lane = tid & 63;
    const int wave = tid >> 6;
    const int wr = wave >> 1, wc = wave & 1;
    const int m0 = blockIdx.x * 128, n0 = blockIdx.y * 128;
    const int fr = lane & 15;          // fragment row (A:m, B:n)
    const int fq = lane >> 4;          // k-quad
    const int srow = tid >> 2;         // staging row 0..63
    const int skg  = (tid & 3) << 3;   // staging k offset in elements

    const unsigned short* gA = A + (size_t)(m0 + srow) * lda + skg;
    const unsigned short* gB = B + (size_t)(n0 + srow) * ldb + skg;
    const size_t a64 = (size_t)64 * lda, b64 = (size_t)64 * ldb;
    short* lA = As + tid * 8;          // byte off = wave*1024 + lane*16 (wave-uniform + lane*16)
    short* lB = Bs + tid * 8;

    floatx4 acc[4][4] = {};

    for (int k0 = 0; k0 < K; k0 += 32) {
        __syncthreads();
        GLOAD_LDS16(gA,       lA);
        GLOAD_LDS16(gA + a64, lA + 2048);
        GLOAD_LDS16(gB,       lB);
        GLOAD_LDS16(gB + b64, lB + 2048);
        gA += 32; gB += 32;
        __syncthreads();
        short8 af[4], bf[4];
#pragma unroll
        for (int i = 0; i < 4; i++) {
            af[i] = *(const short8*)(As + (wr * 64 + i * 16 + fr) * 32 + fq * 8);
            bf[i] = *(const short8*)(Bs + (wc * 64 + i * 16 + fr) * 32 + fq * 8);
        }
#pragma unroll
        for (int mi = 0; mi < 4; mi++)
#pragma unroll
            for (int ni = 0; ni < 4; ni++)
                acc[mi][ni] = __builtin_amdgcn_mfma_f32_16x16x32_bf16(af[mi], bf[ni], acc[mi][ni], 0, 0, 0);
    }

    const float rs = (EPI == 2) ? *e1 : 0.f;
#pragma unroll
    for (int mi = 0; mi < 4; mi++) {
#pragma unroll
        for (int ni = 0; ni < 4; ni++) {
            const int n = n0 + wc * 64 + ni * 16 + fr;
#pragma unroll
            for (int r = 0; r < 4; r++) {
                const int m = m0 + wr * 64 + mi * 16 + fq * 4 + r;
                float v = acc[mi][ni][r];
                if (EPI == 2) v = e0[(size_t)m * ldc + n] + rs * v;
                C[(size_t)m * ldc + n] = v;
            }
        }
    }
}

__device__ __forceinline__ float softplusf(float x) {
    return x > 20.f ? x : log1pf(expf(x));
}

// ---------------- Generic NT fp32 GEMM (kept for the two small GEMMs) ----------
template <int EPI>
__global__ __launch_bounds__(256) void gemm_nt(const float* __restrict__ A, int lda,
                                               const float* __restrict__ B, int ldb,
                                               float* __restrict__ C, int ldc,
                                               int M, int N, int K,
                                               const float* __restrict__ e0,
                                               const float* __restrict__ e1) {
    __shared__ float Asm[16][68];
    __shared__ float Bsm[16][68];
    const int m0 = blockIdx.x * 64, n0 = blockIdx.y * 64;
    const int tid = threadIdx.x;
    const int lr = tid >> 2;
    const int lk = (tid & 3) << 2;
    const int tx = tid & 15;
    const int ty = tid >> 4;
    float acc[4][4] = {};

    for (int k0 = 0; k0 < K; k0 += 16) {
        float4 av = *(const float4*)(A + (size_t)(m0 + lr) * lda + k0 + lk);
        float4 bv = make_float4(0.f, 0.f, 0.f, 0.f);
        int brow = n0 + lr;
        if (brow < N) bv = *(const float4*)(B + (size_t)brow * ldb + k0 + lk);
        __syncthreads();
        Asm[lk + 0][lr] = av.x; Asm[lk + 1][lr] = av.y;
        Asm[lk + 2][lr] = av.z; Asm[lk + 3][lr] = av.w;
        Bsm[lk + 0][lr] = bv.x; Bsm[lk + 1][lr] = bv.y;
        Bsm[lk + 2][lr] = bv.z; Bsm[lk + 3][lr] = bv.w;
        __syncthreads();
#pragma unroll
        for (int kk = 0; kk < 16; kk++) {
            float4 a = *(const float4*)&Asm[kk][tx * 4];
            float4 b = *(const float4*)&Bsm[kk][ty * 4];
            acc[0][0] += a.x * b.x; acc[0][1] += a.x * b.y; acc[0][2] += a.x * b.z; acc[0][3] += a.x * b.w;
            acc[1][0] += a.y * b.x; acc[1][1] += a.y * b.y; acc[1][2] += a.y * b.z; acc[1][3] += a.y * b.w;
            acc[2][0] += a.z * b.x; acc[2][1] += a.z * b.y; acc[2][2] += a.z * b.z; acc[2][3] += a.z * b.w;
            acc[3][0] += a.w * b.x; acc[3][1] += a.w * b.y; acc[3][2] += a.w * b.z; acc[3][3] += a.w * b.w;
        }
    }

    const int n = n0 + ty * 4;
    if (n < N) {
#pragma unroll
        for (int i = 0; i < 4; i++) {
            int m = m0 + tx * 4 + i;
            float4 o;
            if (EPI == 0) {
                o = make_float4(acc[i][0], acc[i][1], acc[i][2], acc[i][3]);
            } else {
                o.x = softplusf(acc[i][0] + e0[n + 0]);
                o.y = softplusf(acc[i][1] + e0[n + 1]);
                o.z = softplusf(acc[i][2] + e0[n + 2]);
                o.w = softplusf(acc[i][3] + e0[n + 3]);
            }
            *(float4*)(C + (size_t)m * ldc + n) = o;
        }
    }
}

// ---------------- depthwise causal conv (k=4) + SiLU ----------------
__global__ __launch_bounds__(256) void conv_silu(const float* __restrict__ xz,
                                                 const float* __restrict__ cw,
                                                 const float* __restrict__ cb,
                                                 float* __restrict__ xc) {
    int idx = blockIdx.x * 256 + threadIdx.x;
    int d = idx & (DINNER - 1);
    int m = idx >> 11;
    int t = m & (LSEQ - 1);
    float v = cb[d];
#pragma unroll
    for (int k = 0; k < 4; k++) {
        int tt = t - 3 + k;
        if (tt >= 0) v += xz[(size_t)(m - 3 + k) * (2 * DINNER) + d] * cw[d * 4 + k];
    }
    v = v / (1.f + __expf(-v));
    xc[idx] = v;
}

// ---------------- selective scan, chunked 3-pass ----------------
__global__ __launch_bounds__(256) void scan_pass1(const float* __restrict__ dt,
                                                  const float* __restrict__ xc,
                                                  const float* __restrict__ xdbl,
                                                  const float* __restrict__ A_log,
                                                  float* __restrict__ Pp,
                                                  float* __restrict__ Sp) {
    const int d = blockIdx.x * 256 + threadIdx.x;
    const int c = blockIdx.y;
    const int b = blockIdx.z;
    __shared__ float Bsm[LCHUNK][DSTATE];
    const size_t rowbase = (size_t)b * LSEQ + (size_t)c * LCHUNK;
    for (int idx = threadIdx.x; idx < LCHUNK * DSTATE; idx += 256) {
        int i = idx >> 4, j = idx & 15;
        Bsm[i][j] = xdbl[(rowbase + i) * NDBL + DTRANK + j];
    }
    __syncthreads();
    float A[DSTATE], P[DSTATE], S[DSTATE];
#pragma unroll
    for (int s = 0; s < DSTATE; s++) {
        A[s] = -__expf(A_log[d * DSTATE + s]);
        P[s] = 1.f; S[s] = 0.f;
    }
    for (int t = 0; t < LCHUNK; t++) {
        float dtv = dt[(rowbase + t) * DINNER + d];
        float xv  = xc[(rowbase + t) * DINNER + d];
        float du = dtv * xv;
#pragma unroll
        for (int s = 0; s < DSTATE; s++) {
            float dA = __expf(dtv * A[s]);
            P[s] *= dA;
            S[s] = S[s] * dA + du * Bsm[t][s];
        }
    }
    const size_t obase = (((size_t)c * 2 + b) * DINNER + d) * DSTATE;
#pragma unroll
    for (int s = 0; s < DSTATE; s++) { Pp[obase + s] = P[s]; Sp[obase + s] = S[s]; }
}

__global__ __launch_bounds__(256) void scan_pass2(float* __restrict__ Pp,
                                                  const float* __restrict__ Sp) {
    const int gid = blockIdx.x * 256 + threadIdx.x;
    const int b = gid >> 15;
    const int rest = gid & 32767;
    float h = 0.f;
    for (int c = 0; c < NCHUNK; c++) {
        size_t idx = ((size_t)(c * 2 + b) << 15) + rest;
        float p = Pp[idx];
        float s = Sp[idx];
        Pp[idx] = h;
        h = p * h + s;
    }
}

// Pass 3: recompute from h_init; y = (sum h*C) + D*x, z-gate; bf16 out.
__global__ __launch_bounds__(256) void scan_pass3(const float* __restrict__ dt,
                                                  const float* __restrict__ xc,
                                                  const float* __restrict__ xdbl,
                                                  const float* __restrict__ xz,
                                                  const float* __restrict__ A_log,
                                                  const float* __restrict__ Dp,
                                                  const float* __restrict__ Hinit,
                                                  unsigned short* __restrict__ y_bf) {
    const int d = blockIdx.x * 256 + threadIdx.x;
    const int c = blockIdx.y;
    const int b = blockIdx.z;
    __shared__ float Bsm[LCHUNK][DSTATE];
    __shared__ float Csm[LCHUNK][DSTATE];
    const size_t rowbase = (size_t)b * LSEQ + (size_t)c * LCHUNK;
    for (int idx = threadIdx.x; idx < LCHUNK * DSTATE; idx += 256) {
        int i = idx >> 4, j = idx & 15;
        Bsm[i][j] = xdbl[(rowbase + i) * NDBL + DTRANK + j];
        Csm[i][j] = xdbl[(rowbase + i) * NDBL + DTRANK + DSTATE + j];
    }
    __syncthreads();
    float A[DSTATE], h[DSTATE];
    const size_t hbase = (((size_t)c * 2 + b) * DINNER + d) * DSTATE;
#pragma unroll
    for (int s = 0; s < DSTATE; s++) {
        A[s] = -__expf(A_log[d * DSTATE + s]);
        h[s] = Hinit[hbase + s];
    }
    const float Dd = Dp[d];
    for (int t = 0; t < LCHUNK; t++) {
        const size_t mi = rowbase + t;
        float dtv = dt[mi * DINNER + d];
        float xv  = xc[mi * DINNER + d];
        float du = dtv * xv;
        float y = 0.f;
#pragma unroll
        for (int s = 0; s < DSTATE; s++) {
            float dA = __expf(dtv * A[s]);
            h[s] = h[s] * dA + du * Bsm[t][s];
            y += h[s] * Csm[t][s];
        }
        y += Dd * xv;
        float zv = xz[mi * (2 * DINNER) + DINNER + d];
        y *= zv / (1.f + __expf(-zv));
        y_bf[mi * DINNER + d] = f2bf(y);
    }
}

extern "C" void kernel_launch(void* const* d_in, const int* in_sizes, int n_in,
                              void* d_out, int out_size, void* d_ws, size_t ws_size,
                              hipStream_t stream) {
    const float* seq       = (const float*)d_in[0];
    const float* ln_g      = (const float*)d_in[1];
    const float* ln_b      = (const float*)d_in[2];
    const float* in_proj_w = (const float*)d_in[3];
    const float* conv_w    = (const float*)d_in[4];
    const float* conv_b    = (const float*)d_in[5];
    const float* x_proj_w  = (const float*)d_in[6];
    const float* dt_proj_w = (const float*)d_in[7];
    const float* dt_proj_b = (const float*)d_in[8];
    const float* A_log     = (const float*)d_in[9];
    const float* Dp        = (const float*)d_in[10];
    const float* out_proj_w= (const float*)d_in[11];
    const float* res_scale = (const float*)d_in[12];

    float* ws   = (float*)d_ws;
    float* xz   = ws;                       // 16,777,216 f  (64MB)
    float* xc   = xz + 16777216;            //  8,388,608 f  (32MB)
    float* dty  = xc + 8388608;             //  8,388,608 f  (32MB) dt
    float* xdbl = dty + 8388608;            //    393,216 f  (1.5MB)
    float* Pp   = xdbl + 393216;            //  4,194,304 f  (16MB) P, then h_init
    float* Sp   = Pp + 4194304;             //  4,194,304 f  (16MB) S
    // aliases (lifetimes disjoint with Pp/Sp scan usage):
    unsigned short* w_in_bf  = (unsigned short*)Pp;              // 8MB, dead before pass1 writes Pp
    unsigned short* xn_bf    = (unsigned short*)Sp;              // 8MB, dead before pass1 writes Sp
    unsigned short* y_bf     = (unsigned short*)Sp;              // 16MB, written by pass3 after Sp dead
    unsigned short* w_out_bf = (unsigned short*)(Sp + 4194304);  // 4MB, own slot

    convert_w<<<6144, 256, 0, stream>>>(in_proj_w, out_proj_w, w_in_bf, w_out_bf);

    ln_kernel<<<MROWS, 256, 0, stream>>>(seq, ln_g, ln_b, xn_bf);

    // xz = xn @ in_proj_w^T   (M=4096, N=4096, K=1024), bf16 MFMA
    gemm_bf16<0><<<dim3(32, 32), 256, 0, stream>>>(xn_bf, DMODEL, w_in_bf, DMODEL,
                                                   xz, 2 * DINNER, DMODEL, nullptr, nullptr);

    conv_silu<<<(MROWS * DINNER) / 256, 256, 0, stream>>>(xz, conv_w, conv_b, xc);

    // x_dbl = xc @ x_proj_w^T   (M=4096, N=96, K=2048), fp32
    gemm_nt<0><<<dim3(64, 2), 256, 0, stream>>>(xc, DINNER, x_proj_w, DINNER,
                                                xdbl, NDBL, MROWS, NDBL, DINNER,
                                                nullptr, nullptr);

    // dt = softplus(x_dbl[:, :64] @ dt_proj_w^T + b)   (M=4096, N=2048, K=64), fp32
    gemm_nt<1><<<dim3(64, 32), 256, 0, stream>>>(xdbl, NDBL, dt_proj_w, DTRANK,
                                                 dty, DINNER, MROWS, DINNER, DTRANK,
                                                 dt_proj_b, nullptr);

    // chunked selective scan
    scan_pass1<<<dim3(DINNER / 256, NCHUNK, 2), 256, 0, stream>>>(dty, xc, xdbl, A_log, Pp, Sp);
    scan_pass2<<<(2 * DINNER * DSTATE) / 256, 256, 0, stream>>>(Pp, Sp);
    scan_pass3<<<dim3(DINNER / 256, NCHUNK, 2), 256, 0, stream>>>(dty, xc, xdbl, xz, A_log, Dp, Pp, y_bf);

    // out = seq + rs * (y @ out_proj_w^T)   (M=4096, N=1024, K=2048), bf16 MFMA
    gemm_bf16<2><<<dim3(32, 8), 256, 0, stream>>>(y_bf, DINNER, w_out_bf, DINNER,
                                                  (float*)d_out, DMODEL, DINNER,
                                                  seq, res_scale);
}

// Round 4
// 420.524 us; speedup vs baseline: 5.5621x; 1.1857x over previous
//
#include <hip/hip_runtime.h>
#include <cmath>

#define MROWS  4096   // B*L
#define DMODEL 1024
#define DINNER 2048
#define DSTATE 16
#define DTRANK 64
#define NDBL   96     // DTRANK + 2*DSTATE
#define LSEQ   2048
#define LCHUNK 32
#define NCHUNK 64     // LSEQ / LCHUNK
#define XPK    8      // x_proj split-K factor
#define XPKS   (DINNER / XPK)   // 256 k per slice

typedef __attribute__((ext_vector_type(8))) short short8;
typedef __attribute__((ext_vector_type(4))) float floatx4;

__device__ __forceinline__ unsigned short f2bf(float x) {   // RNE fp32->bf16
    union { float f; unsigned u; } v; v.f = x;
    unsigned r = v.u + 0x7fff + ((v.u >> 16) & 1);
    return (unsigned short)(r >> 16);
}

#define GLOAD_LDS16(g, l) \
    __builtin_amdgcn_global_load_lds((const __attribute__((address_space(1))) unsigned int*)(g), \
                                     (__attribute__((address_space(3))) unsigned int*)(l), 16, 0, 0)

// ---------------- weight fp32 -> bf16 convert (both proj weights) ----------------
__global__ __launch_bounds__(256) void convert_w(const float* __restrict__ w_in,
                                                 const float* __restrict__ w_out,
                                                 unsigned short* __restrict__ win_bf,
                                                 unsigned short* __restrict__ wout_bf) {
    int idx = blockIdx.x * 256 + threadIdx.x;          // float4 index
    const float4* src; unsigned short* dst; int i;
    if (idx < 1048576) { src = (const float4*)w_in;  dst = win_bf;  i = idx; }
    else               { src = (const float4*)w_out; dst = wout_bf; i = idx - 1048576; }
    float4 v = src[i];
    ushort4 o;
    o.x = f2bf(v.x); o.y = f2bf(v.y); o.z = f2bf(v.z); o.w = f2bf(v.w);
    *(ushort4*)(dst + (size_t)i * 4) = o;
}

// ---------------- LayerNorm: one block per row, bf16 output ----------------
__global__ __launch_bounds__(256) void ln_kernel(const float* __restrict__ seq,
                                                 const float* __restrict__ g,
                                                 const float* __restrict__ bta,
                                                 unsigned short* __restrict__ xn_bf) {
    int row = blockIdx.x;
    int t = threadIdx.x;
    const float4* in4 = (const float4*)(seq + (size_t)row * DMODEL);
    float4 v = in4[t];
    float s  = v.x + v.y + v.z + v.w;
    float s2 = v.x*v.x + v.y*v.y + v.z*v.z + v.w*v.w;
    for (int off = 32; off; off >>= 1) {
        s  += __shfl_down(s,  off, 64);
        s2 += __shfl_down(s2, off, 64);
    }
    __shared__ float ss[4], ss2[4];
    int wid = t >> 6;
    if ((t & 63) == 0) { ss[wid] = s; ss2[wid] = s2; }
    __syncthreads();
    s  = ss[0] + ss[1] + ss[2] + ss[3];
    s2 = ss2[0] + ss2[1] + ss2[2] + ss2[3];
    float mu  = s * (1.0f / DMODEL);
    float var = s2 * (1.0f / DMODEL) - mu * mu;
    float rs  = rsqrtf(var + 1e-5f);
    float4 gg = ((const float4*)g)[t];
    float4 bb = ((const float4*)bta)[t];
    ushort4 o;
    o.x = f2bf((v.x - mu) * rs * gg.x + bb.x);
    o.y = f2bf((v.y - mu) * rs * gg.y + bb.y);
    o.z = f2bf((v.z - mu) * rs * gg.z + bb.z);
    o.w = f2bf((v.w - mu) * rs * gg.w + bb.w);
    *(ushort4*)(xn_bf + (size_t)row * DMODEL + t * 4) = o;
}

// ---------------- bf16 MFMA NT GEMM: C[m,n] = dot(A[m,:], B[n,:]) ----------------
// 128x128 tile, BK=32, 4 waves (2x2), each wave 64x64 via 4x4 of 16x16x32 MFMA.
// EPI 0: plain fp32 store. EPI 2: C = e0[m*ldc+n] + (*e1)*acc  (residual).
template <int EPI>
__global__ __launch_bounds__(256) void gemm_bf16(const unsigned short* __restrict__ A, int lda,
                                                 const unsigned short* __restrict__ B, int ldb,
                                                 float* __restrict__ C, int ldc, int K,
                                                 const float* __restrict__ e0,
                                                 const float* __restrict__ e1) {
    __shared__ short As[128 * 32];
    __shared__ short Bs[128 * 32];
    const int tid  = threadIdx.x;
    const int lane = tid & 63;
    const int wave = tid >> 6;
    const int wr = wave >> 1, wc = wave & 1;
    const int m0 = blockIdx.x * 128, n0 = blockIdx.y * 128;
    const int fr = lane & 15;          // fragment row (A:m, B:n)
    const int fq = lane >> 4;          // k-quad
    const int srow = tid >> 2;         // staging row 0..63
    const int skg  = (tid & 3) << 3;   // staging k offset in elements

    const unsigned short* gA = A + (size_t)(m0 + srow) * lda + skg;
    const unsigned short* gB = B + (size_t)(n0 + srow) * ldb + skg;
    const size_t a64 = (size_t)64 * lda, b64 = (size_t)64 * ldb;
    short* lA = As + tid * 8;
    short* lB = Bs + tid * 8;

    floatx4 acc[4][4] = {};

    for (int k0 = 0; k0 < K; k0 += 32) {
        __syncthreads();
        GLOAD_LDS16(gA,       lA);
        GLOAD_LDS16(gA + a64, lA + 2048);
        GLOAD_LDS16(gB,       lB);
        GLOAD_LDS16(gB + b64, lB + 2048);
        gA += 32; gB += 32;
        __syncthreads();
        short8 af[4], bf[4];
#pragma unroll
        for (int i = 0; i < 4; i++) {
            af[i] = *(const short8*)(As + (wr * 64 + i * 16 + fr) * 32 + fq * 8);
            bf[i] = *(const short8*)(Bs + (wc * 64 + i * 16 + fr) * 32 + fq * 8);
        }
#pragma unroll
        for (int mi = 0; mi < 4; mi++)
#pragma unroll
            for (int ni = 0; ni < 4; ni++)
                acc[mi][ni] = __builtin_amdgcn_mfma_f32_16x16x32_bf16(af[mi], bf[ni], acc[mi][ni], 0, 0, 0);
    }

    const float rs = (EPI == 2) ? *e1 : 0.f;
#pragma unroll
    for (int mi = 0; mi < 4; mi++) {
#pragma unroll
        for (int ni = 0; ni < 4; ni++) {
            const int n = n0 + wc * 64 + ni * 16 + fr;
#pragma unroll
            for (int r = 0; r < 4; r++) {
                const int m = m0 + wr * 64 + mi * 16 + fq * 4 + r;
                float v = acc[mi][ni][r];
                if (EPI == 2) v = e0[(size_t)m * ldc + n] + rs * v;
                C[(size_t)m * ldc + n] = v;
            }
        }
    }
}

__device__ __forceinline__ float softplusf(float x) {
    return x > 20.f ? x : log1pf(expf(x));
}

// ---------------- Generic NT fp32 GEMM (dt GEMM) ----------
template <int EPI>
__global__ __launch_bounds__(256) void gemm_nt(const float* __restrict__ A, int lda,
                                               const float* __restrict__ B, int ldb,
                                               float* __restrict__ C, int ldc,
                                               int M, int N, int K,
                                               const float* __restrict__ e0,
                                               const float* __restrict__ e1) {
    __shared__ float Asm[16][68];
    __shared__ float Bsm[16][68];
    const int m0 = blockIdx.x * 64, n0 = blockIdx.y * 64;
    const int tid = threadIdx.x;
    const int lr = tid >> 2;
    const int lk = (tid & 3) << 2;
    const int tx = tid & 15;
    const int ty = tid >> 4;
    float acc[4][4] = {};

    for (int k0 = 0; k0 < K; k0 += 16) {
        float4 av = *(const float4*)(A + (size_t)(m0 + lr) * lda + k0 + lk);
        float4 bv = make_float4(0.f, 0.f, 0.f, 0.f);
        int brow = n0 + lr;
        if (brow < N) bv = *(const float4*)(B + (size_t)brow * ldb + k0 + lk);
        __syncthreads();
        Asm[lk + 0][lr] = av.x; Asm[lk + 1][lr] = av.y;
        Asm[lk + 2][lr] = av.z; Asm[lk + 3][lr] = av.w;
        Bsm[lk + 0][lr] = bv.x; Bsm[lk + 1][lr] = bv.y;
        Bsm[lk + 2][lr] = bv.z; Bsm[lk + 3][lr] = bv.w;
        __syncthreads();
#pragma unroll
        for (int kk = 0; kk < 16; kk++) {
            float4 a = *(const float4*)&Asm[kk][tx * 4];
            float4 b = *(const float4*)&Bsm[kk][ty * 4];
            acc[0][0] += a.x * b.x; acc[0][1] += a.x * b.y; acc[0][2] += a.x * b.z; acc[0][3] += a.x * b.w;
            acc[1][0] += a.y * b.x; acc[1][1] += a.y * b.y; acc[1][2] += a.y * b.z; acc[1][3] += a.y * b.w;
            acc[2][0] += a.z * b.x; acc[2][1] += a.z * b.y; acc[2][2] += a.z * b.z; acc[2][3] += a.z * b.w;
            acc[3][0] += a.w * b.x; acc[3][1] += a.w * b.y; acc[3][2] += a.w * b.z; acc[3][3] += a.w * b.w;
        }
    }

    const int n = n0 + ty * 4;
    if (n < N) {
#pragma unroll
        for (int i = 0; i < 4; i++) {
            int m = m0 + tx * 4 + i;
            float4 o;
            if (EPI == 0) {
                o = make_float4(acc[i][0], acc[i][1], acc[i][2], acc[i][3]);
            } else {
                o.x = softplusf(acc[i][0] + e0[n + 0]);
                o.y = softplusf(acc[i][1] + e0[n + 1]);
                o.z = softplusf(acc[i][2] + e0[n + 2]);
                o.w = softplusf(acc[i][3] + e0[n + 3]);
            }
            *(float4*)(C + (size_t)m * ldc + n) = o;
        }
    }
}

// ---------------- x_proj split-K GEMM: partials over 8 K-slices ----------------
// Grid (64, 2, XPK). Slice z covers k in [z*XPKS, (z+1)*XPKS).
__global__ __launch_bounds__(256) void xproj_splitk(const float* __restrict__ A,   // xc, lda=DINNER
                                                    const float* __restrict__ B,   // x_proj_w, ldb=DINNER
                                                    float* __restrict__ part) {    // [XPK][MROWS][NDBL]
    __shared__ float Asm[16][68];
    __shared__ float Bsm[16][68];
    const int m0 = blockIdx.x * 64, n0 = blockIdx.y * 64;
    const int koff = blockIdx.z * XPKS;
    const int tid = threadIdx.x;
    const int lr = tid >> 2;
    const int lk = (tid & 3) << 2;
    const int tx = tid & 15;
    const int ty = tid >> 4;
    float acc[4][4] = {};

    for (int k0 = koff; k0 < koff + XPKS; k0 += 16) {
        float4 av = *(const float4*)(A + (size_t)(m0 + lr) * DINNER + k0 + lk);
        float4 bv = make_float4(0.f, 0.f, 0.f, 0.f);
        int brow = n0 + lr;
        if (brow < NDBL) bv = *(const float4*)(B + (size_t)brow * DINNER + k0 + lk);
        __syncthreads();
        Asm[lk + 0][lr] = av.x; Asm[lk + 1][lr] = av.y;
        Asm[lk + 2][lr] = av.z; Asm[lk + 3][lr] = av.w;
        Bsm[lk + 0][lr] = bv.x; Bsm[lk + 1][lr] = bv.y;
        Bsm[lk + 2][lr] = bv.z; Bsm[lk + 3][lr] = bv.w;
        __syncthreads();
#pragma unroll
        for (int kk = 0; kk < 16; kk++) {
            float4 a = *(const float4*)&Asm[kk][tx * 4];
            float4 b = *(const float4*)&Bsm[kk][ty * 4];
            acc[0][0] += a.x * b.x; acc[0][1] += a.x * b.y; acc[0][2] += a.x * b.z; acc[0][3] += a.x * b.w;
            acc[1][0] += a.y * b.x; acc[1][1] += a.y * b.y; acc[1][2] += a.y * b.z; acc[1][3] += a.y * b.w;
            acc[2][0] += a.z * b.x; acc[2][1] += a.z * b.y; acc[2][2] += a.z * b.z; acc[2][3] += a.z * b.w;
            acc[3][0] += a.w * b.x; acc[3][1] += a.w * b.y; acc[3][2] += a.w * b.z; acc[3][3] += a.w * b.w;
        }
    }

    const int n = n0 + ty * 4;
    if (n < NDBL) {
        float* cz = part + (size_t)blockIdx.z * MROWS * NDBL;
#pragma unroll
        for (int i = 0; i < 4; i++) {
            int m = m0 + tx * 4 + i;
            *(float4*)(cz + (size_t)m * NDBL + n) =
                make_float4(acc[i][0], acc[i][1], acc[i][2], acc[i][3]);
        }
    }
}

// Sum the XPK partial slices into x_dbl. float4-vectorized.
__global__ __launch_bounds__(256) void xproj_reduce(const float* __restrict__ part,
                                                    float* __restrict__ xdbl) {
    int idx = blockIdx.x * 256 + threadIdx.x;          // float4 index, 98304 total
    float4 s = ((const float4*)part)[idx];
#pragma unroll
    for (int z = 1; z < XPK; z++) {
        float4 v = ((const float4*)(part + (size_t)z * MROWS * NDBL))[idx];
        s.x += v.x; s.y += v.y; s.z += v.z; s.w += v.w;
    }
    ((float4*)xdbl)[idx] = s;
}

// ---------------- depthwise causal conv (k=4) + SiLU ----------------
__global__ __launch_bounds__(256) void conv_silu(const float* __restrict__ xz,
                                                 const float* __restrict__ cw,
                                                 const float* __restrict__ cb,
                                                 float* __restrict__ xc) {
    int idx = blockIdx.x * 256 + threadIdx.x;
    int d = idx & (DINNER - 1);
    int m = idx >> 11;
    int t = m & (LSEQ - 1);
    float v = cb[d];
#pragma unroll
    for (int k = 0; k < 4; k++) {
        int tt = t - 3 + k;
        if (tt >= 0) v += xz[(size_t)(m - 3 + k) * (2 * DINNER) + d] * cw[d * 4 + k];
    }
    v = v / (1.f + __expf(-v));
    xc[idx] = v;
}

// ---------------- selective scan, chunked 3-pass ----------------
__global__ __launch_bounds__(256) void scan_pass1(const float* __restrict__ dt,
                                                  const float* __restrict__ xc,
                                                  const float* __restrict__ xdbl,
                                                  const float* __restrict__ A_log,
                                                  float* __restrict__ Pp,
                                                  float* __restrict__ Sp) {
    const int d = blockIdx.x * 256 + threadIdx.x;
    const int c = blockIdx.y;
    const int b = blockIdx.z;
    __shared__ float Bsm[LCHUNK][DSTATE];
    const size_t rowbase = (size_t)b * LSEQ + (size_t)c * LCHUNK;
    for (int idx = threadIdx.x; idx < LCHUNK * DSTATE; idx += 256) {
        int i = idx >> 4, j = idx & 15;
        Bsm[i][j] = xdbl[(rowbase + i) * NDBL + DTRANK + j];
    }
    __syncthreads();
    float A[DSTATE], P[DSTATE], S[DSTATE];
#pragma unroll
    for (int s = 0; s < DSTATE; s++) {
        A[s] = -__expf(A_log[d * DSTATE + s]);
        P[s] = 1.f; S[s] = 0.f;
    }
    for (int t = 0; t < LCHUNK; t++) {
        float dtv = dt[(rowbase + t) * DINNER + d];
        float xv  = xc[(rowbase + t) * DINNER + d];
        float du = dtv * xv;
#pragma unroll
        for (int s = 0; s < DSTATE; s++) {
            float dA = __expf(dtv * A[s]);
            P[s] *= dA;
            S[s] = S[s] * dA + du * Bsm[t][s];
        }
    }
    const size_t obase = (((size_t)c * 2 + b) * DINNER + d) * DSTATE;
#pragma unroll
    for (int s = 0; s < DSTATE; s++) { Pp[obase + s] = P[s]; Sp[obase + s] = S[s]; }
}

__global__ __launch_bounds__(256) void scan_pass2(float* __restrict__ Pp,
                                                  const float* __restrict__ Sp) {
    const int gid = blockIdx.x * 256 + threadIdx.x;
    const int b = gid >> 15;
    const int rest = gid & 32767;
    float h = 0.f;
    for (int c = 0; c < NCHUNK; c++) {
        size_t idx = ((size_t)(c * 2 + b) << 15) + rest;
        float p = Pp[idx];
        float s = Sp[idx];
        Pp[idx] = h;
        h = p * h + s;
    }
}

// Pass 3: recompute from h_init; y = (sum h*C) + D*x, z-gate; bf16 out.
__global__ __launch_bounds__(256) void scan_pass3(const float* __restrict__ dt,
                                                  const float* __restrict__ xc,
                                                  const float* __restrict__ xdbl,
                                                  const float* __restrict__ xz,
                                                  const float* __restrict__ A_log,
                                                  const float* __restrict__ Dp,
                                                  const float* __restrict__ Hinit,
                                                  unsigned short* __restrict__ y_bf) {
    const int d = blockIdx.x * 256 + threadIdx.x;
    const int c = blockIdx.y;
    const int b = blockIdx.z;
    __shared__ float Bsm[LCHUNK][DSTATE];
    __shared__ float Csm[LCHUNK][DSTATE];
    const size_t rowbase = (size_t)b * LSEQ + (size_t)c * LCHUNK;
    for (int idx = threadIdx.x; idx < LCHUNK * DSTATE; idx += 256) {
        int i = idx >> 4, j = idx & 15;
        Bsm[i][j] = xdbl[(rowbase + i) * NDBL + DTRANK + j];
        Csm[i][j] = xdbl[(rowbase + i) * NDBL + DTRANK + DSTATE + j];
    }
    __syncthreads();
    float A[DSTATE], h[DSTATE];
    const size_t hbase = (((size_t)c * 2 + b) * DINNER + d) * DSTATE;
#pragma unroll
    for (int s = 0; s < DSTATE; s++) {
        A[s] = -__expf(A_log[d * DSTATE + s]);
        h[s] = Hinit[hbase + s];
    }
    const float Dd = Dp[d];
    for (int t = 0; t < LCHUNK; t++) {
        const size_t mi = rowbase + t;
        float dtv = dt[mi * DINNER + d];
        float xv  = xc[mi * DINNER + d];
        float du = dtv * xv;
        float y = 0.f;
#pragma unroll
        for (int s = 0; s < DSTATE; s++) {
            float dA = __expf(dtv * A[s]);
            h[s] = h[s] * dA + du * Bsm[t][s];
            y += h[s] * Csm[t][s];
        }
        y += Dd * xv;
        float zv = xz[mi * (2 * DINNER) + DINNER + d];
        y *= zv / (1.f + __expf(-zv));
        y_bf[mi * DINNER + d] = f2bf(y);
    }
}

extern "C" void kernel_launch(void* const* d_in, const int* in_sizes, int n_in,
                              void* d_out, int out_size, void* d_ws, size_t ws_size,
                              hipStream_t stream) {
    const float* seq       = (const float*)d_in[0];
    const float* ln_g      = (const float*)d_in[1];
    const float* ln_b      = (const float*)d_in[2];
    const float* in_proj_w = (const float*)d_in[3];
    const float* conv_w    = (const float*)d_in[4];
    const float* conv_b    = (const float*)d_in[5];
    const float* x_proj_w  = (const float*)d_in[6];
    const float* dt_proj_w = (const float*)d_in[7];
    const float* dt_proj_b = (const float*)d_in[8];
    const float* A_log     = (const float*)d_in[9];
    const float* Dp        = (const float*)d_in[10];
    const float* out_proj_w= (const float*)d_in[11];
    const float* res_scale = (const float*)d_in[12];

    float* ws   = (float*)d_ws;
    float* xz   = ws;                       // 16,777,216 f  (64MB)
    float* xc   = xz + 16777216;            //  8,388,608 f  (32MB)
    float* dty  = xc + 8388608;             //  8,388,608 f  (32MB) dt
    float* xdbl = dty + 8388608;            //    393,216 f  (1.5MB)
    float* Pp   = xdbl + 393216;            //  4,194,304 f  (16MB) w_in_bf -> xproj partials -> h_init
    float* Sp   = Pp + 4194304;             //  4,194,304 f  (16MB) xn_bf -> S -> y_bf
    // aliases (lifetimes disjoint):
    unsigned short* w_in_bf  = (unsigned short*)Pp;              // dead after in_proj GEMM
    float*          xp_part  = Pp;                                // 12.6MB, dead before scan_pass1
    unsigned short* xn_bf    = (unsigned short*)Sp;              // dead after in_proj GEMM
    unsigned short* y_bf     = (unsigned short*)Sp;              // written by pass3 after Sp dead
    unsigned short* w_out_bf = (unsigned short*)(Sp + 4194304);  // 4MB, own slot

    convert_w<<<6144, 256, 0, stream>>>(in_proj_w, out_proj_w, w_in_bf, w_out_bf);

    ln_kernel<<<MROWS, 256, 0, stream>>>(seq, ln_g, ln_b, xn_bf);

    // xz = xn @ in_proj_w^T   (M=4096, N=4096, K=1024), bf16 MFMA
    gemm_bf16<0><<<dim3(32, 32), 256, 0, stream>>>(xn_bf, DMODEL, w_in_bf, DMODEL,
                                                   xz, 2 * DINNER, DMODEL, nullptr, nullptr);

    conv_silu<<<(MROWS * DINNER) / 256, 256, 0, stream>>>(xz, conv_w, conv_b, xc);

    // x_dbl = xc @ x_proj_w^T   (M=4096, N=96, K=2048), fp32 split-K=8
    xproj_splitk<<<dim3(64, 2, XPK), 256, 0, stream>>>(xc, x_proj_w, xp_part);
    xproj_reduce<<<(MROWS * NDBL / 4) / 256, 256, 0, stream>>>(xp_part, xdbl);

    // dt = softplus(x_dbl[:, :64] @ dt_proj_w^T + b)   (M=4096, N=2048, K=64), fp32
    gemm_nt<1><<<dim3(64, 32), 256, 0, stream>>>(xdbl, NDBL, dt_proj_w, DTRANK,
                                                 dty, DINNER, MROWS, DINNER, DTRANK,
                                                 dt_proj_b, nullptr);

    // chunked selective scan
    scan_pass1<<<dim3(DINNER / 256, NCHUNK, 2), 256, 0, stream>>>(dty, xc, xdbl, A_log, Pp, Sp);
    scan_pass2<<<(2 * DINNER * DSTATE) / 256, 256, 0, stream>>>(Pp, Sp);
    scan_pass3<<<dim3(DINNER / 256, NCHUNK, 2), 256, 0, stream>>>(dty, xc, xdbl, xz, A_log, Dp, Pp, y_bf);

    // out = seq + rs * (y @ out_proj_w^T)   (M=4096, N=1024, K=2048), bf16 MFMA
    gemm_bf16<2><<<dim3(32, 8), 256, 0, stream>>>(y_bf, DINNER, w_out_bf, DINNER,
                                                  (float*)d_out, DMODEL, DINNER,
                                                  seq, res_scale);
}

// Round 5
// 373.887 us; speedup vs baseline: 6.2559x; 1.1247x over previous
//
#include <hip/hip_runtime.h>
#include <cmath>

#define MROWS  4096   // B*L
#define DMODEL 1024
#define DINNER 2048
#define DSTATE 16
#define DTRANK 64
#define NDBL   96     // DTRANK + 2*DSTATE
#define LSEQ   2048
#define LCHUNK 32
#define NCHUNK 64     // LSEQ / LCHUNK
#define XPK    8      // x_proj split-K factor
#define XPKS   (DINNER / XPK)   // 256 k per slice

typedef __attribute__((ext_vector_type(8))) short short8;
typedef __attribute__((ext_vector_type(4))) float floatx4;

__device__ __forceinline__ unsigned short f2bf(float x) {   // RNE fp32->bf16
    union { float f; unsigned u; } v; v.f = x;
    unsigned r = v.u + 0x7fff + ((v.u >> 16) & 1);
    return (unsigned short)(r >> 16);
}
__device__ __forceinline__ float bf2f(unsigned short u) {
    union { unsigned u; float f; } v; v.u = ((unsigned)u) << 16; return v.f;
}

#define GLOAD_LDS16(g, l) \
    __builtin_amdgcn_global_load_lds((const __attribute__((address_space(1))) unsigned int*)(g), \
                                     (__attribute__((address_space(3))) unsigned int*)(l), 16, 0, 0)

// ---------------- weight fp32 -> bf16 convert (both proj weights) ----------------
__global__ __launch_bounds__(256) void convert_w(const float* __restrict__ w_in,
                                                 const float* __restrict__ w_out,
                                                 unsigned short* __restrict__ win_bf,
                                                 unsigned short* __restrict__ wout_bf) {
    int idx = blockIdx.x * 256 + threadIdx.x;          // float4 index
    const float4* src; unsigned short* dst; int i;
    if (idx < 1048576) { src = (const float4*)w_in;  dst = win_bf;  i = idx; }
    else               { src = (const float4*)w_out; dst = wout_bf; i = idx - 1048576; }
    float4 v = src[i];
    ushort4 o;
    o.x = f2bf(v.x); o.y = f2bf(v.y); o.z = f2bf(v.z); o.w = f2bf(v.w);
    *(ushort4*)(dst + (size_t)i * 4) = o;
}

// ---------------- LayerNorm: one block per row, bf16 output ----------------
__global__ __launch_bounds__(256) void ln_kernel(const float* __restrict__ seq,
                                                 const float* __restrict__ g,
                                                 const float* __restrict__ bta,
                                                 unsigned short* __restrict__ xn_bf) {
    int row = blockIdx.x;
    int t = threadIdx.x;
    const float4* in4 = (const float4*)(seq + (size_t)row * DMODEL);
    float4 v = in4[t];
    float s  = v.x + v.y + v.z + v.w;
    float s2 = v.x*v.x + v.y*v.y + v.z*v.z + v.w*v.w;
    for (int off = 32; off; off >>= 1) {
        s  += __shfl_down(s,  off, 64);
        s2 += __shfl_down(s2, off, 64);
    }
    __shared__ float ss[4], ss2[4];
    int wid = t >> 6;
    if ((t & 63) == 0) { ss[wid] = s; ss2[wid] = s2; }
    __syncthreads();
    s  = ss[0] + ss[1] + ss[2] + ss[3];
    s2 = ss2[0] + ss2[1] + ss2[2] + ss2[3];
    float mu  = s * (1.0f / DMODEL);
    float var = s2 * (1.0f / DMODEL) - mu * mu;
    float rs  = rsqrtf(var + 1e-5f);
    float4 gg = ((const float4*)g)[t];
    float4 bb = ((const float4*)bta)[t];
    ushort4 o;
    o.x = f2bf((v.x - mu) * rs * gg.x + bb.x);
    o.y = f2bf((v.y - mu) * rs * gg.y + bb.y);
    o.z = f2bf((v.z - mu) * rs * gg.z + bb.z);
    o.w = f2bf((v.w - mu) * rs * gg.w + bb.w);
    *(ushort4*)(xn_bf + (size_t)row * DMODEL + t * 4) = o;
}

// ---------------- bf16 MFMA NT GEMM: C[m,n] = dot(A[m,:], B[n,:]) ----------------
// 128x128 tile, BK=32, 4 waves (2x2), each wave 64x64 via 4x4 of 16x16x32 MFMA.
// LDS xor-swizzle: lane (row srow, kgroup kg) stages global kgroup kg^(srow&3),
// so LDS[r][kg] holds global group kg^(r&3); reader fetches column fq^(r&3).
// Split-K via blockIdx.z: slice z covers k in [z*K, (z+1)*K), writes C + z*cstride.
// EPI 0: plain fp32 store.
template <int EPI>
__global__ __launch_bounds__(256) void gemm_bf16(const unsigned short* __restrict__ A, int lda,
                                                 const unsigned short* __restrict__ B, int ldb,
                                                 float* __restrict__ C, int ldc, int K,
                                                 size_t cstride) {
    __shared__ short As[128 * 32];
    __shared__ short Bs[128 * 32];
    const int tid  = threadIdx.x;
    const int lane = tid & 63;
    const int wave = tid >> 6;
    const int wr = wave >> 1, wc = wave & 1;
    const int m0 = blockIdx.x * 128, n0 = blockIdx.y * 128;
    const int koff = blockIdx.z * K;
    const int fr = lane & 15;          // fragment row (A:m, B:n)
    const int fq = lane >> 4;          // k-quad
    const int srow = tid >> 2;         // staging row 0..63
    const int skg  = (((tid & 3) ^ (srow & 3)) << 3);   // swizzled staging k offset

    const unsigned short* gA = A + (size_t)(m0 + srow) * lda + koff + skg;
    const unsigned short* gB = B + (size_t)(n0 + srow) * ldb + koff + skg;
    const size_t a64 = (size_t)64 * lda, b64 = (size_t)64 * ldb;
    short* lA = As + tid * 8;
    short* lB = Bs + tid * 8;
    const int cg = fq ^ (fr & 3);      // swizzled read column group

    floatx4 acc[4][4] = {};

    for (int k0 = 0; k0 < K; k0 += 32) {
        __syncthreads();
        GLOAD_LDS16(gA,       lA);
        GLOAD_LDS16(gA + a64, lA + 2048);
        GLOAD_LDS16(gB,       lB);
        GLOAD_LDS16(gB + b64, lB + 2048);
        gA += 32; gB += 32;
        __syncthreads();
        short8 af[4], bf[4];
#pragma unroll
        for (int i = 0; i < 4; i++) {
            af[i] = *(const short8*)(As + (wr * 64 + i * 16 + fr) * 32 + cg * 8);
            bf[i] = *(const short8*)(Bs + (wc * 64 + i * 16 + fr) * 32 + cg * 8);
        }
#pragma unroll
        for (int mi = 0; mi < 4; mi++)
#pragma unroll
            for (int ni = 0; ni < 4; ni++)
                acc[mi][ni] = __builtin_amdgcn_mfma_f32_16x16x32_bf16(af[mi], bf[ni], acc[mi][ni], 0, 0, 0);
    }

    C += (size_t)blockIdx.z * cstride;
#pragma unroll
    for (int mi = 0; mi < 4; mi++) {
#pragma unroll
        for (int ni = 0; ni < 4; ni++) {
            const int n = n0 + wc * 64 + ni * 16 + fr;
#pragma unroll
            for (int r = 0; r < 4; r++) {
                const int m = m0 + wr * 64 + mi * 16 + fq * 4 + r;
                C[(size_t)m * ldc + n] = acc[mi][ni][r];
            }
        }
    }
}

// out = seq + rs * (p0 + p1)   (out_proj split-K reduce, float4)
__global__ __launch_bounds__(256) void out_reduce(const float* __restrict__ part,
                                                  const float* __restrict__ seq,
                                                  const float* __restrict__ rs_p,
                                                  float* __restrict__ out) {
    int i = blockIdx.x * 256 + threadIdx.x;    // float4 idx, 1,048,576 total
    float rs = *rs_p;
    float4 p0 = ((const float4*)part)[i];
    float4 p1 = ((const float4*)(part + (size_t)MROWS * DMODEL))[i];
    float4 sv = ((const float4*)seq)[i];
    float4 o;
    o.x = sv.x + rs * (p0.x + p1.x);
    o.y = sv.y + rs * (p0.y + p1.y);
    o.z = sv.z + rs * (p0.z + p1.z);
    o.w = sv.w + rs * (p0.w + p1.w);
    ((float4*)out)[i] = o;
}

__device__ __forceinline__ float softplusf(float x) {
    return x > 20.f ? x : log1pf(expf(x));
}

// ---------------- Generic NT fp32 GEMM (dt GEMM) ----------
template <int EPI>
__global__ __launch_bounds__(256) void gemm_nt(const float* __restrict__ A, int lda,
                                               const float* __restrict__ B, int ldb,
                                               float* __restrict__ C, int ldc,
                                               int M, int N, int K,
                                               const float* __restrict__ e0,
                                               const float* __restrict__ e1) {
    __shared__ float Asm[16][68];
    __shared__ float Bsm[16][68];
    const int m0 = blockIdx.x * 64, n0 = blockIdx.y * 64;
    const int tid = threadIdx.x;
    const int lr = tid >> 2;
    const int lk = (tid & 3) << 2;
    const int tx = tid & 15;
    const int ty = tid >> 4;
    float acc[4][4] = {};

    for (int k0 = 0; k0 < K; k0 += 16) {
        float4 av = *(const float4*)(A + (size_t)(m0 + lr) * lda + k0 + lk);
        float4 bv = make_float4(0.f, 0.f, 0.f, 0.f);
        int brow = n0 + lr;
        if (brow < N) bv = *(const float4*)(B + (size_t)brow * ldb + k0 + lk);
        __syncthreads();
        Asm[lk + 0][lr] = av.x; Asm[lk + 1][lr] = av.y;
        Asm[lk + 2][lr] = av.z; Asm[lk + 3][lr] = av.w;
        Bsm[lk + 0][lr] = bv.x; Bsm[lk + 1][lr] = bv.y;
        Bsm[lk + 2][lr] = bv.z; Bsm[lk + 3][lr] = bv.w;
        __syncthreads();
#pragma unroll
        for (int kk = 0; kk < 16; kk++) {
            float4 a = *(const float4*)&Asm[kk][tx * 4];
            float4 b = *(const float4*)&Bsm[kk][ty * 4];
            acc[0][0] += a.x * b.x; acc[0][1] += a.x * b.y; acc[0][2] += a.x * b.z; acc[0][3] += a.x * b.w;
            acc[1][0] += a.y * b.x; acc[1][1] += a.y * b.y; acc[1][2] += a.y * b.z; acc[1][3] += a.y * b.w;
            acc[2][0] += a.z * b.x; acc[2][1] += a.z * b.y; acc[2][2] += a.z * b.z; acc[2][3] += a.z * b.w;
            acc[3][0] += a.w * b.x; acc[3][1] += a.w * b.y; acc[3][2] += a.w * b.z; acc[3][3] += a.w * b.w;
        }
    }

    const int n = n0 + ty * 4;
    if (n < N) {
#pragma unroll
        for (int i = 0; i < 4; i++) {
            int m = m0 + tx * 4 + i;
            float4 o;
            if (EPI == 0) {
                o = make_float4(acc[i][0], acc[i][1], acc[i][2], acc[i][3]);
            } else {
                o.x = softplusf(acc[i][0] + e0[n + 0]);
                o.y = softplusf(acc[i][1] + e0[n + 1]);
                o.z = softplusf(acc[i][2] + e0[n + 2]);
                o.w = softplusf(acc[i][3] + e0[n + 3]);
            }
            *(float4*)(C + (size_t)m * ldc + n) = o;
        }
    }
}

// ---------------- x_proj split-K GEMM over bf16 xc: partials over 8 K-slices ----------------
__global__ __launch_bounds__(256) void xproj_splitk(const unsigned short* __restrict__ A,  // xc bf16, lda=DINNER
                                                    const float* __restrict__ B,           // x_proj_w, ldb=DINNER
                                                    float* __restrict__ part) {            // [XPK][MROWS][NDBL]
    __shared__ float Asm[16][68];
    __shared__ float Bsm[16][68];
    const int m0 = blockIdx.x * 64, n0 = blockIdx.y * 64;
    const int koff = blockIdx.z * XPKS;
    const int tid = threadIdx.x;
    const int lr = tid >> 2;
    const int lk = (tid & 3) << 2;
    const int tx = tid & 15;
    const int ty = tid >> 4;
    float acc[4][4] = {};

    for (int k0 = koff; k0 < koff + XPKS; k0 += 16) {
        ushort4 au = *(const ushort4*)(A + (size_t)(m0 + lr) * DINNER + k0 + lk);
        float4 av = make_float4(bf2f(au.x), bf2f(au.y), bf2f(au.z), bf2f(au.w));
        float4 bv = make_float4(0.f, 0.f, 0.f, 0.f);
        int brow = n0 + lr;
        if (brow < NDBL) bv = *(const float4*)(B + (size_t)brow * DINNER + k0 + lk);
        __syncthreads();
        Asm[lk + 0][lr] = av.x; Asm[lk + 1][lr] = av.y;
        Asm[lk + 2][lr] = av.z; Asm[lk + 3][lr] = av.w;
        Bsm[lk + 0][lr] = bv.x; Bsm[lk + 1][lr] = bv.y;
        Bsm[lk + 2][lr] = bv.z; Bsm[lk + 3][lr] = bv.w;
        __syncthreads();
#pragma unroll
        for (int kk = 0; kk < 16; kk++) {
            float4 a = *(const float4*)&Asm[kk][tx * 4];
            float4 b = *(const float4*)&Bsm[kk][ty * 4];
            acc[0][0] += a.x * b.x; acc[0][1] += a.x * b.y; acc[0][2] += a.x * b.z; acc[0][3] += a.x * b.w;
            acc[1][0] += a.y * b.x; acc[1][1] += a.y * b.y; acc[1][2] += a.y * b.z; acc[1][3] += a.y * b.w;
            acc[2][0] += a.z * b.x; acc[2][1] += a.z * b.y; acc[2][2] += a.z * b.z; acc[2][3] += a.z * b.w;
            acc[3][0] += a.w * b.x; acc[3][1] += a.w * b.y; acc[3][2] += a.w * b.z; acc[3][3] += a.w * b.w;
        }
    }

    const int n = n0 + ty * 4;
    if (n < NDBL) {
        float* cz = part + (size_t)blockIdx.z * MROWS * NDBL;
#pragma unroll
        for (int i = 0; i < 4; i++) {
            int m = m0 + tx * 4 + i;
            *(float4*)(cz + (size_t)m * NDBL + n) =
                make_float4(acc[i][0], acc[i][1], acc[i][2], acc[i][3]);
        }
    }
}

// Sum the XPK partial slices into x_dbl. float4-vectorized.
__global__ __launch_bounds__(256) void xproj_reduce(const float* __restrict__ part,
                                                    float* __restrict__ xdbl) {
    int idx = blockIdx.x * 256 + threadIdx.x;          // float4 index, 98304 total
    float4 s = ((const float4*)part)[idx];
#pragma unroll
    for (int z = 1; z < XPK; z++) {
        float4 v = ((const float4*)(part + (size_t)z * MROWS * NDBL))[idx];
        s.x += v.x; s.y += v.y; s.z += v.z; s.w += v.w;
    }
    ((float4*)xdbl)[idx] = s;
}

// ---------------- depthwise causal conv (k=4) + SiLU, 4 t per thread, bf16 out ----
__global__ __launch_bounds__(256) void conv_silu(const float* __restrict__ xz,
                                                 const float* __restrict__ cw,
                                                 const float* __restrict__ cb,
                                                 unsigned short* __restrict__ xc) {
    int gid = blockIdx.x * 256 + threadIdx.x;    // 2,097,152 threads
    int d  = gid & (DINNER - 1);
    int mq = gid >> 11;                          // 0..1023
    int b  = mq >> 9;
    int t0 = (mq & 511) << 2;                    // 0,4,...,2044
    const float* xrow = xz + (size_t)(b * LSEQ + t0) * (2 * DINNER) + d;
    float x[7];
#pragma unroll
    for (int j = 0; j < 7; j++) {
        int t = t0 + j - 3;
        x[j] = (t >= 0) ? xrow[(ptrdiff_t)(j - 3) * (2 * DINNER)] : 0.f;
    }
    const float w0 = cw[d * 4 + 0], w1 = cw[d * 4 + 1],
                w2 = cw[d * 4 + 2], w3 = cw[d * 4 + 3], bz = cb[d];
    unsigned short* orow = xc + (size_t)(b * LSEQ + t0) * DINNER + d;
#pragma unroll
    for (int j = 0; j < 4; j++) {
        float v = bz + x[j] * w0 + x[j + 1] * w1 + x[j + 2] * w2 + x[j + 3] * w3;
        v = v / (1.f + __expf(-v));
        orow[(size_t)j * DINNER] = f2bf(v);
    }
}

// ---------------- selective scan, chunked 3-pass ----------------
__global__ __launch_bounds__(256) void scan_pass1(const float* __restrict__ dt,
                                                  const unsigned short* __restrict__ xc,
                                                  const float* __restrict__ xdbl,
                                                  const float* __restrict__ A_log,
                                                  float* __restrict__ Pp,
                                                  float* __restrict__ Sp) {
    const int d = blockIdx.x * 256 + threadIdx.x;
    const int c = blockIdx.y;
    const int b = blockIdx.z;
    __shared__ float Bsm[LCHUNK][DSTATE];
    const size_t rowbase = (size_t)b * LSEQ + (size_t)c * LCHUNK;
    for (int idx = threadIdx.x; idx < LCHUNK * DSTATE; idx += 256) {
        int i = idx >> 4, j = idx & 15;
        Bsm[i][j] = xdbl[(rowbase + i) * NDBL + DTRANK + j];
    }
    __syncthreads();
    float A[DSTATE], P[DSTATE], S[DSTATE];
#pragma unroll
    for (int s = 0; s < DSTATE; s++) {
        A[s] = -__expf(A_log[d * DSTATE + s]);
        P[s] = 1.f; S[s] = 0.f;
    }
    for (int t = 0; t < LCHUNK; t++) {
        float dtv = dt[(rowbase + t) * DINNER + d];
        float xv  = bf2f(xc[(rowbase + t) * DINNER + d]);
        float du = dtv * xv;
#pragma unroll
        for (int s = 0; s < DSTATE; s++) {
            float dA = __expf(dtv * A[s]);
            P[s] *= dA;
            S[s] = S[s] * dA + du * Bsm[t][s];
        }
    }
    const size_t obase = (((size_t)c * 2 + b) * DINNER + d) * DSTATE;
#pragma unroll
    for (int s = 0; s < DSTATE; s++) { Pp[obase + s] = P[s]; Sp[obase + s] = S[s]; }
}

__global__ __launch_bounds__(256) void scan_pass2(float* __restrict__ Pp,
                                                  const float* __restrict__ Sp) {
    const int gid = blockIdx.x * 256 + threadIdx.x;
    const int b = gid >> 15;
    const int rest = gid & 32767;
    float h = 0.f;
    for (int c = 0; c < NCHUNK; c++) {
        size_t idx = ((size_t)(c * 2 + b) << 15) + rest;
        float p = Pp[idx];
        float s = Sp[idx];
        Pp[idx] = h;
        h = p * h + s;
    }
}

// Pass 3: recompute from h_init; y = (sum h*C) + D*x, z-gate; bf16 out.
__global__ __launch_bounds__(256) void scan_pass3(const float* __restrict__ dt,
                                                  const unsigned short* __restrict__ xc,
                                                  const float* __restrict__ xdbl,
                                                  const float* __restrict__ xz,
                                                  const float* __restrict__ A_log,
                                                  const float* __restrict__ Dp,
                                                  const float* __restrict__ Hinit,
                                                  unsigned short* __restrict__ y_bf) {
    const int d = blockIdx.x * 256 + threadIdx.x;
    const int c = blockIdx.y;
    const int b = blockIdx.z;
    __shared__ float Bsm[LCHUNK][DSTATE];
    __shared__ float Csm[LCHUNK][DSTATE];
    const size_t rowbase = (size_t)b * LSEQ + (size_t)c * LCHUNK;
    for (int idx = threadIdx.x; idx < LCHUNK * DSTATE; idx += 256) {
        int i = idx >> 4, j = idx & 15;
        Bsm[i][j] = xdbl[(rowbase + i) * NDBL + DTRANK + j];
        Csm[i][j] = xdbl[(rowbase + i) * NDBL + DTRANK + DSTATE + j];
    }
    __syncthreads();
    float A[DSTATE], h[DSTATE];
    const size_t hbase = (((size_t)c * 2 + b) * DINNER + d) * DSTATE;
#pragma unroll
    for (int s = 0; s < DSTATE; s++) {
        A[s] = -__expf(A_log[d * DSTATE + s]);
        h[s] = Hinit[hbase + s];
    }
    const float Dd = Dp[d];
    for (int t = 0; t < LCHUNK; t++) {
        const size_t mi = rowbase + t;
        float dtv = dt[mi * DINNER + d];
        float xv  = bf2f(xc[mi * DINNER + d]);
        float du = dtv * xv;
        float y = 0.f;
#pragma unroll
        for (int s = 0; s < DSTATE; s++) {
            float dA = __expf(dtv * A[s]);
            h[s] = h[s] * dA + du * Bsm[t][s];
            y += h[s] * Csm[t][s];
        }
        y += Dd * xv;
        float zv = xz[mi * (2 * DINNER) + DINNER + d];
        y *= zv / (1.f + __expf(-zv));
        y_bf[mi * DINNER + d] = f2bf(y);
    }
}

extern "C" void kernel_launch(void* const* d_in, const int* in_sizes, int n_in,
                              void* d_out, int out_size, void* d_ws, size_t ws_size,
                              hipStream_t stream) {
    const float* seq       = (const float*)d_in[0];
    const float* ln_g      = (const float*)d_in[1];
    const float* ln_b      = (const float*)d_in[2];
    const float* in_proj_w = (const float*)d_in[3];
    const float* conv_w    = (const float*)d_in[4];
    const float* conv_b    = (const float*)d_in[5];
    const float* x_proj_w  = (const float*)d_in[6];
    const float* dt_proj_w = (const float*)d_in[7];
    const float* dt_proj_b = (const float*)d_in[8];
    const float* A_log     = (const float*)d_in[9];
    const float* Dp        = (const float*)d_in[10];
    const float* out_proj_w= (const float*)d_in[11];
    const float* res_scale = (const float*)d_in[12];

    float* ws   = (float*)d_ws;
    float* xz   = ws;                          // 16,777,216 f (64MB); reused for out_proj partials
    unsigned short* xc = (unsigned short*)(xz + 16777216);   // 8,388,608 bf16 (16MB)
    float* dty  = xz + 16777216 + 4194304;     //  8,388,608 f (32MB) dt
    float* xdbl = dty + 8388608;               //    393,216 f (1.5MB)
    float* Pp   = xdbl + 393216;               //  4,194,304 f (16MB) w_in_bf -> xproj partials -> h_init
    float* Sp   = Pp + 4194304;                //  4,194,304 f (16MB) xn_bf -> S -> y_bf
    // aliases (lifetimes disjoint):
    unsigned short* w_in_bf  = (unsigned short*)Pp;              // dead after in_proj GEMM
    float*          xp_part  = Pp;                               // 12.6MB, dead before scan_pass1
    unsigned short* xn_bf    = (unsigned short*)Sp;              // dead after in_proj GEMM
    unsigned short* y_bf     = (unsigned short*)Sp;              // written by pass3 after Sp dead
    unsigned short* w_out_bf = (unsigned short*)(Sp + 4194304);  // 4MB, own slot
    float*          op_part  = xz;                               // 2 x 16.8MB out_proj partials (xz dead after pass3)

    convert_w<<<6144, 256, 0, stream>>>(in_proj_w, out_proj_w, w_in_bf, w_out_bf);

    ln_kernel<<<MROWS, 256, 0, stream>>>(seq, ln_g, ln_b, xn_bf);

    // xz = xn @ in_proj_w^T   (M=4096, N=4096, K=1024), bf16 MFMA
    gemm_bf16<0><<<dim3(32, 32, 1), 256, 0, stream>>>(xn_bf, DMODEL, w_in_bf, DMODEL,
                                                      xz, 2 * DINNER, DMODEL, 0);

    conv_silu<<<8192, 256, 0, stream>>>(xz, conv_w, conv_b, xc);

    // x_dbl = xc @ x_proj_w^T   (M=4096, N=96, K=2048), fp32 split-K=8
    xproj_splitk<<<dim3(64, 2, XPK), 256, 0, stream>>>(xc, x_proj_w, xp_part);
    xproj_reduce<<<(MROWS * NDBL / 4) / 256, 256, 0, stream>>>(xp_part, xdbl);

    // dt = softplus(x_dbl[:, :64] @ dt_proj_w^T + b)   (M=4096, N=2048, K=64), fp32
    gemm_nt<1><<<dim3(64, 32), 256, 0, stream>>>(xdbl, NDBL, dt_proj_w, DTRANK,
                                                 dty, DINNER, MROWS, DINNER, DTRANK,
                                                 dt_proj_b, nullptr);

    // chunked selective scan
    scan_pass1<<<dim3(DINNER / 256, NCHUNK, 2), 256, 0, stream>>>(dty, xc, xdbl, A_log, Pp, Sp);
    scan_pass2<<<(2 * DINNER * DSTATE) / 256, 256, 0, stream>>>(Pp, Sp);
    scan_pass3<<<dim3(DINNER / 256, NCHUNK, 2), 256, 0, stream>>>(dty, xc, xdbl, xz, A_log, Dp, Pp, y_bf);

    // out_proj partials: p_z = y @ out_proj_w^T over K-slice z (split-K=2 for occupancy)
    gemm_bf16<0><<<dim3(32, 8, 2), 256, 0, stream>>>(y_bf, DINNER, w_out_bf, DINNER,
                                                     op_part, DMODEL, DINNER / 2,
                                                     (size_t)MROWS * DMODEL);

    // out = seq + rs * (p0 + p1)
    out_reduce<<<(MROWS * DMODEL / 4) / 256, 256, 0, stream>>>(op_part, seq, res_scale, (float*)d_out);
}